// Round 3
// baseline (59.484 us; speedup 1.0000x reference)
//
#include <hip/hip_runtime.h>
#include <math.h>

// Problem constants (from setup_inputs): n=16, C=1, H=W=128, nobj=128
#define NN   16
#define NOBJ 128
#define HH   128
#define WW   128
#define TILE_W 32
#define TILE_H 16
// each thread owns 2 pixels: (x,y) and (x,y+8); block = 256 threads
// tiles per image: (128/32) * (128/16) = 4 * 8 = 32  -> grid = 512 blocks

__global__ __launch_bounds__(256) void centernet_gt_kernel(
    const float* __restrict__ bboxes,   // [NN, NOBJ, 5]
    float* __restrict__ out)            // [NN, 1, HH, WW]
{
    // Compacted per-tile object list: .x=cx, .y=cy, .z=r, .w=bits(-1/(2*sigma^2))
    __shared__ int4 s_obj[NOBJ];
    __shared__ int  s_cnt;

    const int tilesPerImg = (WW / TILE_W) * (HH / TILE_H); // 32
    const int tilesX      = WW / TILE_W;                   // 4

    int img  = blockIdx.x / tilesPerImg;
    int tile = blockIdx.x % tilesPerImg;
    int tx0  = (tile % tilesX) * TILE_W;
    int ty0  = (tile / tilesX) * TILE_H;

    int tid = threadIdx.x;

    if (tid == 0) s_cnt = 0;
    __syncthreads();

    // ---- Phase 1: per-object params + tile cull + compaction (threads 0..127)
    if (tid < NOBJ) {
        const float* bb = bboxes + (img * NOBJ + tid) * 5;
        float x1 = bb[0] * 128.0f;
        float y1 = bb[1] * 128.0f;
        float x2 = bb[2] * 128.0f;
        float y2 = bb[3] * 128.0f;
        float v  = bb[4];
        float bw = x2 - x1;
        float bh = y2 - y1;

        // gaussian_radius(bw, bh, min_overlap=0.7) — mirror numpy f32 op order
        float b1 = bh + bw;
        float c1 = bw * bh * 0.3f / 1.7f;
        float r1 = (b1 + sqrtf(b1 * b1 - 4.0f * c1)) * 0.5f;

        float b2 = 2.0f * (bh + bw);
        float c2 = 0.3f * bw * bh;
        float r2 = (b2 + sqrtf(b2 * b2 - 16.0f * c2)) * 0.5f;

        float b3 = -1.4f * (bh + bw);          // -2*0.7*(h+w)
        float c3 = -0.3f * bw * bh;            // (0.7-1)*w*h
        float r3 = (b3 + sqrtf(b3 * b3 - 11.2f * c3)) * 0.5f;  // 4*a3 = 11.2

        float rad = fminf(fminf(r1, r2), r3);
        if (!(rad > 0.0f)) rad = 0.0f;          // nan_to_num + max(.,0)

        int cxi = (int)((x1 + x2) * 0.5f);      // trunc toward zero (nonneg)
        int cyi = (int)((y1 + y2) * 0.5f);
        int ri  = (int)rad;

        bool ok = (v == 1.0f) && (bw > 0.0f) && (bh > 0.0f);
        // tile AABB overlap cull
        bool hit = ok &&
                   (cxi + ri >= tx0) && (cxi - ri < tx0 + TILE_W) &&
                   (cyi + ri >= ty0) && (cyi - ri < ty0 + TILE_H);

        if (hit) {
            float sigma = (float)(2 * ri + 1) / 6.0f;
            float m = -1.0f / (2.0f * sigma * sigma);
            int pos = atomicAdd(&s_cnt, 1);     // LDS atomic; order irrelevant (max)
            s_obj[pos] = make_int4(cxi, cyi, ri, __float_as_int(m));
        }
    }
    __syncthreads();

    // ---- Phase 2: each thread owns pixels (x, y0) and (x, y0+8) ----
    int x  = tx0 + (tid & (TILE_W - 1));
    int y0 = ty0 + (tid >> 5);                  // rows ty0 .. ty0+7
    int y1p = y0 + 8;                           // rows ty0+8 .. ty0+15

    int cnt = s_cnt;
    float acc0 = 0.0f, acc1 = 0.0f;
    for (int o = 0; o < cnt; ++o) {
        int4 ob = s_obj[o];                     // one ds_read_b128 broadcast
        int dx  = x   - ob.x;
        int dy0 = y0  - ob.y;
        int dy1 = y1p - ob.y;
        int r   = ob.z;
        float m = __int_as_float(ob.w);
        bool inx = (dx >= -r) & (dx <= r);
        bool in0 = inx & (dy0 >= -r) & (dy0 <= r);
        bool in1 = inx & (dy1 >= -r) & (dy1 <= r);
        // branchless: exp underflows safely for far pixels
        float g0 = expf((float)(dx * dx + dy0 * dy0) * m);
        float g1 = expf((float)(dx * dx + dy1 * dy1) * m);
        acc0 = fmaxf(acc0, in0 ? g0 : 0.0f);
        acc1 = fmaxf(acc1, in1 ? g1 : 0.0f);
    }

    out[(img * HH + y0 ) * WW + x] = acc0;
    out[(img * HH + y1p) * WW + x] = acc1;
}

extern "C" void kernel_launch(void* const* d_in, const int* in_sizes, int n_in,
                              void* d_out, int out_size, void* d_ws, size_t ws_size,
                              hipStream_t stream) {
    // d_in[0] = hm [16,1,128,128] f32 (only shape matters, unused)
    // d_in[1] = bboxes [16,128,5] f32
    const float* bboxes = (const float*)d_in[1];
    float* out = (float*)d_out;

    const int tilesPerImg = (WW / TILE_W) * (HH / TILE_H); // 32
    dim3 grid(NN * tilesPerImg);                           // 512 blocks
    dim3 block(256);
    centernet_gt_kernel<<<grid, block, 0, stream>>>(bboxes, out);
}

// Round 4
// 58.448 us; speedup vs baseline: 1.0177x; 1.0177x over previous
//
#include <hip/hip_runtime.h>
#include <math.h>

// Problem constants (from setup_inputs): n=16, C=1, H=W=128, nobj=128
#define NN   16
#define NOBJ 128
#define HH   128
#define WW   128
#define TILE_W 32
#define TILE_H 8
// tiles per image: (128/32) * (128/8) = 4 * 16 = 64  -> grid = 1024 blocks
// (R3 A/B: 32x16 tiles / 512 blocks was +1.1us — fewer blocks/CU hurt; keep 1024)

__global__ __launch_bounds__(256) void centernet_gt_kernel(
    const float* __restrict__ bboxes,   // [NN, NOBJ, 5]
    float* __restrict__ out)            // [NN, 1, HH, WW]
{
    // Compacted per-tile object list: .x=cx, .y=cy, .z=r, .w=bits(-1/(2*sigma^2))
    __shared__ int4 s_obj[NOBJ];
    __shared__ int  s_cnt;

    const int tilesPerImg = (WW / TILE_W) * (HH / TILE_H); // 64
    const int tilesX      = WW / TILE_W;                   // 4

    int img  = blockIdx.x / tilesPerImg;
    int tile = blockIdx.x % tilesPerImg;
    int tx0  = (tile % tilesX) * TILE_W;
    int ty0  = (tile / tilesX) * TILE_H;

    int tid = threadIdx.x;

    if (tid == 0) s_cnt = 0;
    __syncthreads();

    // ---- Phase 1: per-object params + tile cull + compaction (threads 0..127)
    if (tid < NOBJ) {
        const float* bb = bboxes + (img * NOBJ + tid) * 5;
        float x1 = bb[0] * 128.0f;
        float y1 = bb[1] * 128.0f;
        float x2 = bb[2] * 128.0f;
        float y2 = bb[3] * 128.0f;
        float v  = bb[4];
        float bw = x2 - x1;
        float bh = y2 - y1;

        // gaussian_radius(bw, bh, min_overlap=0.7) — mirror numpy f32 op order
        float b1 = bh + bw;
        float c1 = bw * bh * 0.3f / 1.7f;
        float r1 = (b1 + sqrtf(b1 * b1 - 4.0f * c1)) * 0.5f;

        float b2 = 2.0f * (bh + bw);
        float c2 = 0.3f * bw * bh;
        float r2 = (b2 + sqrtf(b2 * b2 - 16.0f * c2)) * 0.5f;

        float b3 = -1.4f * (bh + bw);          // -2*0.7*(h+w)
        float c3 = -0.3f * bw * bh;            // (0.7-1)*w*h
        float r3 = (b3 + sqrtf(b3 * b3 - 11.2f * c3)) * 0.5f;  // 4*a3 = 11.2

        float rad = fminf(fminf(r1, r2), r3);
        if (!(rad > 0.0f)) rad = 0.0f;          // nan_to_num + max(.,0)

        int cxi = (int)((x1 + x2) * 0.5f);      // trunc toward zero (nonneg)
        int cyi = (int)((y1 + y2) * 0.5f);
        int ri  = (int)rad;

        bool ok = (v == 1.0f) && (bw > 0.0f) && (bh > 0.0f);
        // tile AABB overlap cull
        bool hit = ok &&
                   (cxi + ri >= tx0) && (cxi - ri < tx0 + TILE_W) &&
                   (cyi + ri >= ty0) && (cyi - ri < ty0 + TILE_H);

        if (hit) {
            float sigma = (float)(2 * ri + 1) / 6.0f;
            float m = -1.0f / (2.0f * sigma * sigma);
            int pos = atomicAdd(&s_cnt, 1);     // LDS atomic; order irrelevant (max)
            s_obj[pos] = make_int4(cxi, cyi, ri, __float_as_int(m));
        }
    }
    __syncthreads();

    // ---- Phase 2: each thread owns one pixel of the tile ----
    int x = tx0 + (tid & (TILE_W - 1));
    int y = ty0 + (tid >> 5);

    int cnt = s_cnt;
    float acc = 0.0f;
    for (int o = 0; o < cnt; ++o) {
        int4 ob = s_obj[o];                     // one ds_read_b128 broadcast
        int dx = x - ob.x;
        int dy = y - ob.y;
        int r  = ob.z;
        bool in = (dx >= -r) & (dx <= r) & (dy >= -r) & (dy <= r);
        // branchless: exp computed unconditionally (underflow is safe), masked select
        float g = expf((float)(dx * dx + dy * dy) * __int_as_float(ob.w));
        acc = fmaxf(acc, in ? g : 0.0f);
    }

    out[(img * HH + y) * WW + x] = acc;
}

extern "C" void kernel_launch(void* const* d_in, const int* in_sizes, int n_in,
                              void* d_out, int out_size, void* d_ws, size_t ws_size,
                              hipStream_t stream) {
    // d_in[0] = hm [16,1,128,128] f32 (only shape matters, unused)
    // d_in[1] = bboxes [16,128,5] f32
    const float* bboxes = (const float*)d_in[1];
    float* out = (float*)d_out;

    const int tilesPerImg = (WW / TILE_W) * (HH / TILE_H); // 64
    dim3 grid(NN * tilesPerImg);                           // 1024 blocks
    dim3 block(256);
    centernet_gt_kernel<<<grid, block, 0, stream>>>(bboxes, out);
}